// Round 1
// baseline (732.089 us; speedup 1.0000x reference)
//
#include <hip/hip_runtime.h>
#include <hip/hip_bf16.h>
#include <math.h>

// Problem constants
constexpr int B  = 128;
constexpr int S  = 128;
constexpr int H  = 1024;
constexpr int E  = 512;
constexpr int V  = 32000;
constexpr int H2 = 2 * H;     // 2048
constexpr int G4 = 4 * H;     // 4096
constexpr int KX = E + H;     // 1536
constexpr int KG = KX + H;    // 2560
constexpr int BS = B * S;     // 16384

typedef float  f32x4  __attribute__((ext_vector_type(4)));
typedef short  short8 __attribute__((ext_vector_type(8)));

// fp32 -> bf16 round-to-nearest-even
__device__ __forceinline__ short f2bf(float f) {
    union { float f; unsigned u; } x; x.f = f;
    unsigned r = (x.u + 0x7FFFu + ((x.u >> 16) & 1u)) >> 16;
    return (short)r;
}
__device__ __forceinline__ float bf2f(unsigned short u) {
    union { unsigned u; float f; } x; x.u = ((unsigned)u) << 16;
    return x.f;
}
__device__ __forceinline__ float fast_tanh(float x) {
    float z = fminf(fmaxf(x, -15.f), 15.f);
    float e = __expf(2.f * z);
    return 1.f - __fdividef(2.f, e + 1.f);
}
__device__ __forceinline__ short8 cvt8(float4 a, float4 b) {
    short8 r;
    r[0] = f2bf(a.x); r[1] = f2bf(a.y); r[2] = f2bf(a.z); r[3] = f2bf(a.w);
    r[4] = f2bf(b.x); r[5] = f2bf(b.y); r[6] = f2bf(b.z); r[7] = f2bf(b.w);
    return r;
}
// async global->LDS, 16B/lane; LDS dest = wave-uniform base + lane*16
__device__ __forceinline__ void glds16(const void* g, void* l) {
    __builtin_amdgcn_global_load_lds(
        (const __attribute__((address_space(1))) unsigned int*)g,
        (__attribute__((address_space(3))) unsigned int*)l,
        16, 0, 0);
}

// ---------------------------------------------------------------------------
// Merged preprocessing: q (512 blocks, FIRST so its L2-bound loops overlap the
// HBM streaming of the cvt blocks), enc->bf16 (16384 blocks), attn_W[:,H:]->bf16
// (1024 blocks).
// ---------------------------------------------------------------------------
__global__ __launch_bounds__(256) void k_pre(const float* __restrict__ enc,
                                             short* __restrict__ encb,
                                             const float* __restrict__ attn_W,
                                             short* __restrict__ w2b,
                                             const float* __restrict__ hlast,
                                             const float* __restrict__ attn_b,
                                             float* __restrict__ q) {
    int bid = blockIdx.x;
    if (bid < 512) {
        // q[b,h] = attn_b[h] + dot(h_last[b,:], attn_W[h, 0:H])
        int idx = bid * 256 + threadIdx.x;
        int b = idx >> 10;
        int h = idx & (H - 1);
        const float* arow = attn_W + (size_t)h * H2;
        const float* hrow = hlast + (size_t)b * H;
        float acc = 0.f;
        for (int k = 0; k < H; k += 4) {
            float4 a = *(const float4*)(arow + k);
            float4 x = *(const float4*)(hrow + k);
            acc += a.x * x.x + a.y * x.y + a.z * x.z + a.w * x.w;
        }
        q[idx] = acc + attn_b[h];
    } else if (bid < 512 + 16384) {
        size_t p = (size_t)(bid - 512) * 256 + threadIdx.x;   // float4 index
        float4 a = *(const float4*)(enc + p * 4);
        short4 o = { f2bf(a.x), f2bf(a.y), f2bf(a.z), f2bf(a.w) };
        *(short4*)(encb + p * 4) = o;
    } else {
        int p = (bid - 16896) * 256 + threadIdx.x;            // 262144 units
        int row = p >> 8;
        int c = (p & 255) * 4;
        float4 a = *(const float4*)(attn_W + (size_t)row * H2 + H + c);
        short4 o = { f2bf(a.x), f2bf(a.y), f2bf(a.z), f2bf(a.w) };
        *(short4*)(w2b + (size_t)row * H + c) = o;
    }
}

// ---------------------------------------------------------------------------
// Energy MFMA GEMM + fused tanh/v/row-reduce (unchanged).
// M=16384 N=1024 K=1024. BM=BN=128, BK=32, 16x16x32 bf16.
// ---------------------------------------------------------------------------
__global__ __launch_bounds__(256) void k_energy_mfma(const short* __restrict__ encb,
                                                     const short* __restrict__ w2b,
                                                     const float* __restrict__ q,
                                                     const float* __restrict__ v,
                                                     float* __restrict__ part) {
    __shared__ __align__(16) short A_s[128 * 32];
    __shared__ __align__(16) short B_s[128 * 32];
    __shared__ float red[128][33];

    const int tid  = threadIdx.x;
    const int wave = tid >> 6, lane = tid & 63;
    const int wr = wave >> 1, wc = wave & 1;
    const int c16 = lane & 15, q4 = lane >> 4;
    const int m0 = blockIdx.x * 128;
    const int n0 = blockIdx.y * 128;

    f32x4 acc[4][4] = {};

    const int u0 = wave * 128 + lane;
    const int rowA0 = u0 >> 2,        rowA1 = (u0 + 64) >> 2;
    const int ofsA0 = (u0 & 3) * 8,   ofsA1 = ((u0 + 64) & 3) * 8;
    short* ldsA0 = A_s + wave * 1024;
    short* ldsA1 = A_s + wave * 1024 + 512;
    short* ldsB0 = B_s + wave * 1024;
    short* ldsB1 = B_s + wave * 1024 + 512;
    const short* gA = encb + (size_t)m0 * H;
    const short* gB = w2b + (size_t)n0 * H;

    for (int k0 = 0; k0 < H; k0 += 32) {
        __syncthreads();
        glds16(gA + (size_t)rowA0 * H + k0 + ofsA0, ldsA0);
        glds16(gA + (size_t)rowA1 * H + k0 + ofsA1, ldsA1);
        glds16(gB + (size_t)rowA0 * H + k0 + ofsA0, ldsB0);
        glds16(gB + (size_t)rowA1 * H + k0 + ofsA1, ldsB1);
        __syncthreads();

        short8 a[4], b[4];
#pragma unroll
        for (int i = 0; i < 4; i++)
            a[i] = *(const short8*)(A_s + (wr * 64 + i * 16 + c16) * 32 + q4 * 8);
#pragma unroll
        for (int j = 0; j < 4; j++)
            b[j] = *(const short8*)(B_s + (wc * 64 + j * 16 + c16) * 32 + q4 * 8);
#pragma unroll
        for (int i = 0; i < 4; i++)
#pragma unroll
            for (int j = 0; j < 4; j++)
                acc[i][j] = __builtin_amdgcn_mfma_f32_16x16x32_bf16(a[i], b[j], acc[i][j], 0, 0, 0);
    }

    const float* qb = q + (size_t)blockIdx.x * H;   // b == blockIdx.x (BM==S)
#pragma unroll
    for (int i = 0; i < 4; i++) {
#pragma unroll
        for (int r = 0; r < 4; r++) {
            float s = 0.f;
#pragma unroll
            for (int j = 0; j < 4; j++) {
                int n = n0 + wc * 64 + j * 16 + c16;
                s += v[n] * fast_tanh(qb[n] + acc[i][j][r]);
            }
            red[wr * 64 + i * 16 + q4 * 4 + r][wc * 16 + c16] = s;
        }
    }
    __syncthreads();
    if (tid < 128) {
        float s = 0.f;
#pragma unroll
        for (int c = 0; c < 32; c++) s += red[tid][c];
        part[(size_t)(m0 + tid) * 8 + blockIdx.y] = s;
    }
}

// ---------------------------------------------------------------------------
// Softmax over S + context, fused with xin packing. Now 4 blocks per batch
// element (softmax recomputed redundantly from part: 4 KB, L2-hot); each
// chunk computes 256 h of the context -> 8 waves/CU instead of 2.
// ---------------------------------------------------------------------------
__global__ __launch_bounds__(256) void k_softmax_ctx(const float* __restrict__ part,
                                                     const short* __restrict__ encb,
                                                     const int* __restrict__ x,
                                                     const float* __restrict__ emb,
                                                     const float* __restrict__ hlast,
                                                     float* __restrict__ attn_out,
                                                     short* __restrict__ xinb) {
    const int bid = blockIdx.x;
    const int b = bid >> 2, ch = bid & 3;
    const int tid = threadIdx.x;
    __shared__ float w[S];
    __shared__ float red[128];

    float val = 0.f;
    if (tid < S) {
        const float* p = part + (size_t)(b * S + tid) * 8;
#pragma unroll
        for (int t = 0; t < 8; t++) val += p[t];
        w[tid] = val;
        red[tid] = val;
    }
    __syncthreads();
#pragma unroll
    for (int s = 64; s > 0; s >>= 1) {
        if (tid < s) red[tid] = fmaxf(red[tid], red[tid + s]);
        __syncthreads();
    }
    float m = red[0];
    __syncthreads();
    if (tid < S) { val = __expf(w[tid] - m); red[tid] = val; }
    __syncthreads();
#pragma unroll
    for (int s = 64; s > 0; s >>= 1) {
        if (tid < s) red[tid] += red[tid + s];
        __syncthreads();
    }
    float inv = 1.f / red[0];
    if (tid < S) {
        val *= inv;
        w[tid] = val;
        if (ch == 0) attn_out[b * S + tid] = val;
    }
    // distribute the independent packing work across chunks
    if (ch == 1) {
        int xv = x[b];
        float2 e2 = *(const float2*)(emb + (size_t)xv * E + tid * 2);
        short2 eo = { f2bf(e2.x), f2bf(e2.y) };
        *(short2*)(xinb + (size_t)b * KG + tid * 2) = eo;
    } else if (ch == 2) {
        float4 h4 = *(const float4*)(hlast + (size_t)b * H + tid * 4);
        short4 ho = { f2bf(h4.x), f2bf(h4.y), f2bf(h4.z), f2bf(h4.w) };
        *(short4*)(xinb + (size_t)b * KG + KX + tid * 4) = ho;
    }
    __syncthreads();

    // context for this chunk's 256 h values (1 h per thread; lanes contiguous)
    const int h = ch * 256 + tid;
    const unsigned short* e = (const unsigned short*)encb + (size_t)b * S * H + h;
    float a0 = 0.f;
#pragma unroll 8
    for (int s = 0; s < S; s++) a0 += w[s] * bf2f(e[(size_t)s * H]);
    xinb[(size_t)b * KG + E + h] = f2bf(a0);
}

// ---------------------------------------------------------------------------
// Gates GEMM, LDS-free direct-fragment version with K-split 2.
// gpart[kh][m,n] = xin[m, kh*1280:+1280] @ [W_ih|W_hh][n, same]
// B-fragment = 8 consecutive fp32 of weight row n (k-major) -> 2 float4 + cvt.
// A (xinb, 640 KB) is L2-resident; per-lane direct short8 fragment loads.
// No __syncthreads -> loads pipeline freely across iterations.
// grid (128, 2), 128 threads (2 independent waves, BN=32).
// ---------------------------------------------------------------------------
__global__ __launch_bounds__(128) void k_gates_direct(const short* __restrict__ xinb,
                                                      const float* __restrict__ W_ih,
                                                      const float* __restrict__ W_hh,
                                                      float* __restrict__ gpart) {
    const int tid  = threadIdx.x;
    const int wave = tid >> 6, lane = tid & 63;
    const int c16 = lane & 15, q4 = lane >> 4;
    const int n = blockIdx.x * 32 + wave * 16 + c16;
    const int kh = blockIdx.y;
    const int kbeg = kh * (KG / 2), kend = kbeg + (KG / 2);   // 1280 each

    const short* arow = xinb + (size_t)c16 * KG;

    auto bptr = [&](int k) -> const float* {
        return (k < KX) ? (W_ih + (size_t)n * KX + k)
                        : (W_hh + (size_t)n * H + (k - KX));
    };

    f32x4 acc[8] = {};
    float4 p0 = *(const float4*)bptr(kbeg + q4 * 8);
    float4 p1 = *(const float4*)bptr(kbeg + q4 * 8 + 4);

    for (int k0 = kbeg; k0 < kend; k0 += 32) {
        short8 bfr = cvt8(p0, p1);
        if (k0 + 32 < kend) {
            p0 = *(const float4*)bptr(k0 + 32 + q4 * 8);
            p1 = *(const float4*)bptr(k0 + 32 + q4 * 8 + 4);
        }
#pragma unroll
        for (int i = 0; i < 8; i++) {
            short8 a = *(const short8*)(arow + (size_t)i * 16 * KG + k0 + q4 * 8);
            acc[i] = __builtin_amdgcn_mfma_f32_16x16x32_bf16(a, bfr, acc[i], 0, 0, 0);
        }
    }

    float* gp = gpart + (size_t)kh * B * G4;
#pragma unroll
    for (int i = 0; i < 8; i++)
#pragma unroll
        for (int r = 0; r < 4; r++)
            gp[(size_t)(i * 16 + q4 * 4 + r) * G4 + n] = acc[i][r];
}

// ---------------------------------------------------------------------------
// LSTM pointwise; sums the two gate partials + biases. Emits
// xout = [bf16(h_new) | bf16(ctx)] (ctx copied from xin, already rounded).
// ---------------------------------------------------------------------------
__global__ __launch_bounds__(256) void k_lstm(const float* __restrict__ gpart,
                                              const float* __restrict__ cell,
                                              const float* __restrict__ b_ih,
                                              const float* __restrict__ b_hh,
                                              const short* __restrict__ xinb,
                                              float* __restrict__ out_h,
                                              float* __restrict__ out_c,
                                              short* __restrict__ xoutb) {
    int idx = blockIdx.x * 256 + threadIdx.x;
    int b = idx >> 10;
    int h = idx & (H - 1);
    const float* g0 = gpart + (size_t)b * G4;
    const float* g1 = gpart + (size_t)B * G4 + (size_t)b * G4;
    float ig = g0[h]         + g1[h]         + b_ih[h]         + b_hh[h];
    float fg = g0[H + h]     + g1[H + h]     + b_ih[H + h]     + b_hh[H + h];
    float gg = g0[2 * H + h] + g1[2 * H + h] + b_ih[2 * H + h] + b_hh[2 * H + h];
    float og = g0[3 * H + h] + g1[3 * H + h] + b_ih[3 * H + h] + b_hh[3 * H + h];
    float si = 1.f / (1.f + expf(-ig));
    float sf = 1.f / (1.f + expf(-fg));
    float so = 1.f / (1.f + expf(-og));
    float c = sf * cell[idx] + si * tanhf(gg);
    float hn = so * tanhf(c);
    out_h[idx] = hn;
    out_c[idx] = c;
    xoutb[(size_t)b * H2 + h] = f2bf(hn);
    xoutb[(size_t)b * H2 + H + h] = xinb[(size_t)b * KG + E + h];
}

// ---------------------------------------------------------------------------
// fc GEMM, LDS-free direct-fragment version. M=128 N=32000 K=2048.
// Barrier-free: B-fragments (8 consecutive fp32 of fc_W row n) stream from
// HBM with a 2-deep register prefetch; A (xoutb, 512 KB) is L2-resident and
// loaded per-lane as short8 fragments. grid 500, 256 thr, wave n-chunk = 16.
// ---------------------------------------------------------------------------
__global__ __launch_bounds__(256) void k_fc_direct(const short* __restrict__ xoutb,
                                                   const float* __restrict__ fcW,
                                                   const float* __restrict__ fcb,
                                                   float* __restrict__ logits) {
    const int tid  = threadIdx.x;
    const int wave = tid >> 6, lane = tid & 63;
    const int c16 = lane & 15, q4 = lane >> 4;
    const int n = blockIdx.x * 64 + wave * 16 + c16;

    const float* brow = fcW + (size_t)n * H2;
    const short* arow = xoutb + (size_t)c16 * H2;

    f32x4 acc[8] = {};

    // 2-deep B prefetch (k0 and k0+32)
    float4 a0 = *(const float4*)(brow + q4 * 8);
    float4 a1 = *(const float4*)(brow + q4 * 8 + 4);
    float4 b0 = *(const float4*)(brow + 32 + q4 * 8);
    float4 b1 = *(const float4*)(brow + 32 + q4 * 8 + 4);

    for (int k0 = 0; k0 < H2; k0 += 64) {
        short8 bfA = cvt8(a0, a1);
        if (k0 + 64 < H2) {
            a0 = *(const float4*)(brow + k0 + 64 + q4 * 8);
            a1 = *(const float4*)(brow + k0 + 64 + q4 * 8 + 4);
        }
#pragma unroll
        for (int i = 0; i < 8; i++) {
            short8 a = *(const short8*)(arow + (size_t)i * 16 * H2 + k0 + q4 * 8);
            acc[i] = __builtin_amdgcn_mfma_f32_16x16x32_bf16(a, bfA, acc[i], 0, 0, 0);
        }
        short8 bfB = cvt8(b0, b1);
        if (k0 + 96 < H2) {
            b0 = *(const float4*)(brow + k0 + 96 + q4 * 8);
            b1 = *(const float4*)(brow + k0 + 96 + q4 * 8 + 4);
        }
#pragma unroll
        for (int i = 0; i < 8; i++) {
            short8 a = *(const short8*)(arow + (size_t)i * 16 * H2 + k0 + 32 + q4 * 8);
            acc[i] = __builtin_amdgcn_mfma_f32_16x16x32_bf16(a, bfB, acc[i], 0, 0, 0);
        }
    }

    const float bias = fcb[n];
#pragma unroll
    for (int i = 0; i < 8; i++)
#pragma unroll
        for (int r = 0; r < 4; r++)
            logits[(size_t)(i * 16 + q4 * 4 + r) * V + n] = acc[i][r] + bias;
}

// ---------------------------------------------------------------------------
extern "C" void kernel_launch(void* const* d_in, const int* in_sizes, int n_in,
                              void* d_out, int out_size, void* d_ws, size_t ws_size,
                              hipStream_t stream) {
    const int*   x      = (const int*)d_in[0];
    const float* hidden = (const float*)d_in[1];
    const float* cell   = (const float*)d_in[2];
    const float* enc    = (const float*)d_in[3];
    const float* emb    = (const float*)d_in[4];
    const float* attn_W = (const float*)d_in[5];
    const float* attn_b = (const float*)d_in[6];
    const float* v      = (const float*)d_in[7];
    const float* W_ih   = (const float*)d_in[8];
    const float* W_hh   = (const float*)d_in[9];
    const float* b_ih   = (const float*)d_in[10];
    const float* b_hh   = (const float*)d_in[11];
    const float* fc_W   = (const float*)d_in[12];
    const float* fc_b   = (const float*)d_in[13];

    float* out = (float*)d_out;
    float* logits   = out;                                   // [B,V]
    float* out_h    = out + (size_t)B * V;                   // [1,B,H]
    float* out_c    = out_h + (size_t)B * H;                 // [1,B,H]
    float* out_attn = out_c + (size_t)B * H;                 // [B,S]

    // workspace layout (16B-aligned)
    char* ws = (char*)d_ws;
    short* encb  = (short*)ws;   ws += (size_t)BS * H * 2;   // 33.5 MB
    short* w2b   = (short*)ws;   ws += (size_t)H * H * 2;    // 2 MB
    short* xinb  = (short*)ws;   ws += (size_t)B * KG * 2;   // 0.66 MB
    short* xoutb = (short*)ws;   ws += (size_t)B * H2 * 2;   // 0.5 MB
    float* q     = (float*)ws;   ws += (size_t)B * H * 4;
    float* part  = (float*)ws;   ws += (size_t)BS * 8 * 4;
    float* gpart = (float*)ws;   ws += (size_t)2 * B * G4 * 4;  // 4 MB

    k_pre<<<dim3(512 + 16384 + 1024), dim3(256), 0, stream>>>(enc, encb, attn_W, w2b,
                                                              hidden, attn_b, q);
    k_energy_mfma<<<dim3(BS / 128, H / 128), dim3(256), 0, stream>>>(encb, w2b, q, v, part);
    k_softmax_ctx<<<dim3(B * 4), dim3(256), 0, stream>>>(part, encb, x, emb, hidden, out_attn, xinb);
    k_gates_direct<<<dim3(G4 / 32, 2), dim3(128), 0, stream>>>(xinb, W_ih, W_hh, gpart);
    k_lstm<<<dim3(B * H / 256), dim3(256), 0, stream>>>(gpart, cell, b_ih, b_hh, xinb,
                                                        out_h, out_c, xoutb);
    k_fc_direct<<<dim3(V / 64), dim3(256), 0, stream>>>(xoutb, fc_W, fc_b, logits);
}

// Round 3
// 640.934 us; speedup vs baseline: 1.1422x; 1.1422x over previous
//
#include <hip/hip_runtime.h>
#include <hip/hip_bf16.h>
#include <math.h>

// Problem constants
constexpr int B  = 128;
constexpr int S  = 128;
constexpr int H  = 1024;
constexpr int E  = 512;
constexpr int V  = 32000;
constexpr int H2 = 2 * H;     // 2048
constexpr int G4 = 4 * H;     // 4096
constexpr int KX = E + H;     // 1536
constexpr int KG = KX + H;    // 2560
constexpr int BS = B * S;     // 16384
constexpr int KSPLIT = 4;
constexpr int KSEG = KG / KSPLIT;  // 640

typedef float  f32x4  __attribute__((ext_vector_type(4)));
typedef short  short8 __attribute__((ext_vector_type(8)));

// fp32 -> bf16 round-to-nearest-even
__device__ __forceinline__ short f2bf(float f) {
    union { float f; unsigned u; } x; x.f = f;
    unsigned r = (x.u + 0x7FFFu + ((x.u >> 16) & 1u)) >> 16;
    return (short)r;
}
__device__ __forceinline__ float bf2f(unsigned short u) {
    union { unsigned u; float f; } x; x.u = ((unsigned)u) << 16;
    return x.f;
}
__device__ __forceinline__ float fast_tanh(float x) {
    float z = fminf(fmaxf(x, -15.f), 15.f);
    float e = __expf(2.f * z);
    return 1.f - __fdividef(2.f, e + 1.f);
}
__device__ __forceinline__ short8 cvt8(float4 a, float4 b) {
    short8 r;
    r[0] = f2bf(a.x); r[1] = f2bf(a.y); r[2] = f2bf(a.z); r[3] = f2bf(a.w);
    r[4] = f2bf(b.x); r[5] = f2bf(b.y); r[6] = f2bf(b.z); r[7] = f2bf(b.w);
    return r;
}
// async global->LDS, 16B/lane; LDS dest = wave-uniform base + lane*16
__device__ __forceinline__ void glds16(const void* g, void* l) {
    __builtin_amdgcn_global_load_lds(
        (const __attribute__((address_space(1))) unsigned int*)g,
        (__attribute__((address_space(3))) unsigned int*)l,
        16, 0, 0);
}

// ---------------------------------------------------------------------------
// Merged preprocessing: q (512 blocks first), enc->bf16 (16384), attn_W[:,H:]
// ->bf16 (1024).
// ---------------------------------------------------------------------------
__global__ __launch_bounds__(256) void k_pre(const float* __restrict__ enc,
                                             short* __restrict__ encb,
                                             const float* __restrict__ attn_W,
                                             short* __restrict__ w2b,
                                             const float* __restrict__ hlast,
                                             const float* __restrict__ attn_b,
                                             float* __restrict__ q) {
    int bid = blockIdx.x;
    if (bid < 512) {
        int idx = bid * 256 + threadIdx.x;
        int b = idx >> 10;
        int h = idx & (H - 1);
        const float* arow = attn_W + (size_t)h * H2;
        const float* hrow = hlast + (size_t)b * H;
        float acc = 0.f;
        for (int k = 0; k < H; k += 4) {
            float4 a = *(const float4*)(arow + k);
            float4 x = *(const float4*)(hrow + k);
            acc += a.x * x.x + a.y * x.y + a.z * x.z + a.w * x.w;
        }
        q[idx] = acc + attn_b[h];
    } else if (bid < 512 + 16384) {
        size_t p = (size_t)(bid - 512) * 256 + threadIdx.x;
        float4 a = *(const float4*)(enc + p * 4);
        short4 o = { f2bf(a.x), f2bf(a.y), f2bf(a.z), f2bf(a.w) };
        *(short4*)(encb + p * 4) = o;
    } else {
        int p = (bid - 16896) * 256 + threadIdx.x;
        int row = p >> 8;
        int c = (p & 255) * 4;
        float4 a = *(const float4*)(attn_W + (size_t)row * H2 + H + c);
        short4 o = { f2bf(a.x), f2bf(a.y), f2bf(a.z), f2bf(a.w) };
        *(short4*)(w2b + (size_t)row * H + c) = o;
    }
}

// ---------------------------------------------------------------------------
// Energy MFMA GEMM + fused tanh/v/row-reduce.
// Double-buffered LDS (1 barrier/iter) + both-sides chunk swizzle
// (stage: src chunk = dest chunk ^ ((row>>1)&3); read: chunk = q4 ^ sa).
// red[] aliases the tile buffers (used only after the K-loop, fenced).
// ---------------------------------------------------------------------------
__global__ __launch_bounds__(256) void k_energy_mfma(const short* __restrict__ encb,
                                                     const short* __restrict__ w2b,
                                                     const float* __restrict__ q,
                                                     const float* __restrict__ v,
                                                     float* __restrict__ part) {
    __shared__ __align__(16) char smem[32768];
    short* Af = (short*)smem;                 // [2][4096] shorts (16 KB)
    short* Bf = (short*)(smem + 16384);       // [2][4096] shorts (16 KB)
    float (*red)[33] = (float(*)[33])smem;    // 16.9 KB, aliases tiles

    const int tid  = threadIdx.x;
    const int wave = tid >> 6, lane = tid & 63;
    const int wr = wave >> 1, wc = wave & 1;
    const int c16 = lane & 15, q4 = lane >> 4;
    const int m0 = blockIdx.x * 128;
    const int n0 = blockIdx.y * 128;

    f32x4 acc[4][4] = {};

    const int scA   = ((lane & 3) ^ ((lane >> 3) & 3)) * 8;   // src short-ofs
    const int rowA0 = wave * 32 + (lane >> 2);
    const int rowA1 = rowA0 + 16;
    const int sa    = (c16 >> 1) & 3;                          // read swizzle

    const short* gA = encb + (size_t)m0 * H;
    const short* gB = w2b + (size_t)n0 * H;

    auto stage = [&](int k0, int dst) {
        glds16(gA + (size_t)rowA0 * H + k0 + scA, Af + dst + wave * 1024);
        glds16(gA + (size_t)rowA1 * H + k0 + scA, Af + dst + wave * 1024 + 512);
        glds16(gB + (size_t)rowA0 * H + k0 + scA, Bf + dst + wave * 1024);
        glds16(gB + (size_t)rowA1 * H + k0 + scA, Bf + dst + wave * 1024 + 512);
    };

    stage(0, 0);
    __syncthreads();

    for (int kk = 0; kk < 32; kk++) {
        const int bo = (kk & 1) << 12;
        if (kk < 31) stage((kk + 1) * 32, bo ^ 4096);

        short8 a[4], b[4];
#pragma unroll
        for (int i = 0; i < 4; i++) {
            int r = wr * 64 + i * 16 + c16;
            a[i] = *(const short8*)(Af + bo + r * 32 + (q4 ^ sa) * 8);
        }
#pragma unroll
        for (int j = 0; j < 4; j++) {
            int r = wc * 64 + j * 16 + c16;
            b[j] = *(const short8*)(Bf + bo + r * 32 + (q4 ^ sa) * 8);
        }
#pragma unroll
        for (int i = 0; i < 4; i++)
#pragma unroll
            for (int j = 0; j < 4; j++)
                acc[i][j] = __builtin_amdgcn_mfma_f32_16x16x32_bf16(a[i], b[j], acc[i][j], 0, 0, 0);

        if (kk < 31) __syncthreads();
    }
    __syncthreads();   // all tile reads done before red[] overwrites them

    const float* qb = q + (size_t)blockIdx.x * H;   // b == blockIdx.x (BM==S)
#pragma unroll
    for (int i = 0; i < 4; i++) {
#pragma unroll
        for (int r = 0; r < 4; r++) {
            float s = 0.f;
#pragma unroll
            for (int j = 0; j < 4; j++) {
                int n = n0 + wc * 64 + j * 16 + c16;
                s += v[n] * fast_tanh(qb[n] + acc[i][j][r]);
            }
            red[wr * 64 + i * 16 + q4 * 4 + r][wc * 16 + c16] = s;
        }
    }
    __syncthreads();
    if (tid < 128) {
        float s = 0.f;
#pragma unroll
        for (int c = 0; c < 32; c++) s += red[tid][c];
        part[(size_t)(m0 + tid) * 8 + blockIdx.y] = s;
    }
}

// ---------------------------------------------------------------------------
// Softmax over S + context, fused with xin packing (4 chunks per b).
// ---------------------------------------------------------------------------
__global__ __launch_bounds__(256) void k_softmax_ctx(const float* __restrict__ part,
                                                     const short* __restrict__ encb,
                                                     const int* __restrict__ x,
                                                     const float* __restrict__ emb,
                                                     const float* __restrict__ hlast,
                                                     float* __restrict__ attn_out,
                                                     short* __restrict__ xinb) {
    const int bid = blockIdx.x;
    const int b = bid >> 2, ch = bid & 3;
    const int tid = threadIdx.x;
    __shared__ float w[S];
    __shared__ float red[128];

    float val = 0.f;
    if (tid < S) {
        const float* p = part + (size_t)(b * S + tid) * 8;
#pragma unroll
        for (int t = 0; t < 8; t++) val += p[t];
        w[tid] = val;
        red[tid] = val;
    }
    __syncthreads();
#pragma unroll
    for (int s = 64; s > 0; s >>= 1) {
        if (tid < s) red[tid] = fmaxf(red[tid], red[tid + s]);
        __syncthreads();
    }
    float m = red[0];
    __syncthreads();
    if (tid < S) { val = __expf(w[tid] - m); red[tid] = val; }
    __syncthreads();
#pragma unroll
    for (int s = 64; s > 0; s >>= 1) {
        if (tid < s) red[tid] += red[tid + s];
        __syncthreads();
    }
    float inv = 1.f / red[0];
    if (tid < S) {
        val *= inv;
        w[tid] = val;
        if (ch == 0) attn_out[b * S + tid] = val;
    }
    if (ch == 1) {
        int xv = x[b];
        float2 e2 = *(const float2*)(emb + (size_t)xv * E + tid * 2);
        short2 eo = { f2bf(e2.x), f2bf(e2.y) };
        *(short2*)(xinb + (size_t)b * KG + tid * 2) = eo;
    } else if (ch == 2) {
        float4 h4 = *(const float4*)(hlast + (size_t)b * H + tid * 4);
        short4 ho = { f2bf(h4.x), f2bf(h4.y), f2bf(h4.z), f2bf(h4.w) };
        *(short4*)(xinb + (size_t)b * KG + KX + tid * 4) = ho;
    }
    __syncthreads();

    const int h = ch * 256 + tid;
    const unsigned short* e = (const unsigned short*)encb + (size_t)b * S * H + h;
    float a0 = 0.f;
#pragma unroll 8
    for (int s = 0; s < S; s++) a0 += w[s] * bf2f(e[(size_t)s * H]);
    xinb[(size_t)b * KG + E + h] = f2bf(a0);
}

// ---------------------------------------------------------------------------
// Gates GEMM: M=128, BN=32, BK=32, K-split 4 (grid 128x4).
// A (xinb bf16) and B (weights, KEPT FP32) both staged via glds16 with
// both-sides swizzle; B converted to bf16 at fragment read. Double-buffered,
// one barrier per K-iter. KSEG=640; KX boundary falls on a 32-multiple so
// each iter's source matrix is uniform.
// ---------------------------------------------------------------------------
__global__ __launch_bounds__(256) void k_gates_mfma(const short* __restrict__ xinb,
                                                    const float* __restrict__ W_ih,
                                                    const float* __restrict__ W_hh,
                                                    float* __restrict__ gpart) {
    __shared__ __align__(16) short A_s[2 * 4096];   // 16 KB
    __shared__ __align__(16) float B_s[2 * 1024];   // 8 KB (fp32 32x32)

    const int tid  = threadIdx.x;
    const int wave = tid >> 6, lane = tid & 63;
    const int c16 = lane & 15, q4 = lane >> 4;
    const int n0 = blockIdx.x * 32;
    const int kbeg = blockIdx.y * KSEG;

    const int scA   = ((lane & 3) ^ ((lane >> 3) & 3)) * 8;
    const int rowA0 = wave * 32 + (lane >> 2);
    const int rowA1 = rowA0 + 16;
    const int rowB  = wave * 8 + (lane >> 3);           // 32 rows, 8 units each
    const int scB   = ((lane & 7) ^ ((lane >> 3) & 7)) * 4;
    const int sa = (c16 >> 1) & 3;
    const int sb = c16 & 7;

    const short* gA0 = xinb + (size_t)rowA0 * KG + scA;
    const short* gA1 = xinb + (size_t)rowA1 * KG + scA;
    const int nr = n0 + rowB;

    auto bsrc = [&](int k0) -> const float* {
        return (k0 < KX) ? (W_ih + (size_t)nr * KX + k0 + scB)
                         : (W_hh + (size_t)nr * H + (k0 - KX) + scB);
    };
    auto stage = [&](int k0, int abo, int bbo) {
        glds16(gA0 + k0, A_s + abo + wave * 1024);
        glds16(gA1 + k0, A_s + abo + wave * 1024 + 512);
        glds16(bsrc(k0), B_s + bbo + wave * 256);
    };

    f32x4 acc[2][2] = {};
    stage(kbeg, 0, 0);
    __syncthreads();

    for (int kk = 0; kk < KSEG / 32; kk++) {
        const int abo = (kk & 1) << 12;
        const int bbo = (kk & 1) << 10;
        if (kk < KSEG / 32 - 1) stage(kbeg + (kk + 1) * 32, abo ^ 4096, bbo ^ 1024);

        short8 a[2], bfr[2];
#pragma unroll
        for (int i = 0; i < 2; i++) {
            int r = wave * 32 + i * 16 + c16;
            a[i] = *(const short8*)(A_s + abo + r * 32 + (q4 ^ sa) * 8);
        }
#pragma unroll
        for (int j = 0; j < 2; j++) {
            int rb = j * 16 + c16;
            int cl = (2 * q4) ^ sb;
            float4 lo = *(const float4*)(B_s + bbo + rb * 32 + cl * 4);
            float4 hi = *(const float4*)(B_s + bbo + rb * 32 + (cl ^ 1) * 4);
            bfr[j] = cvt8(lo, hi);
        }
#pragma unroll
        for (int i = 0; i < 2; i++)
#pragma unroll
            for (int j = 0; j < 2; j++)
                acc[i][j] = __builtin_amdgcn_mfma_f32_16x16x32_bf16(a[i], bfr[j], acc[i][j], 0, 0, 0);

        if (kk < KSEG / 32 - 1) __syncthreads();
    }

    float* gp = gpart + (size_t)blockIdx.y * B * G4;
#pragma unroll
    for (int i = 0; i < 2; i++)
#pragma unroll
        for (int j = 0; j < 2; j++)
#pragma unroll
            for (int r = 0; r < 4; r++) {
                int R = wave * 32 + i * 16 + q4 * 4 + r;
                int n = n0 + j * 16 + c16;
                gp[(size_t)R * G4 + n] = acc[i][j][r];
            }
}

// ---------------------------------------------------------------------------
// LSTM pointwise; sums KSPLIT gate partials + biases.
// ---------------------------------------------------------------------------
__global__ __launch_bounds__(256) void k_lstm(const float* __restrict__ gpart,
                                              const float* __restrict__ cell,
                                              const float* __restrict__ b_ih,
                                              const float* __restrict__ b_hh,
                                              const short* __restrict__ xinb,
                                              float* __restrict__ out_h,
                                              float* __restrict__ out_c,
                                              short* __restrict__ xoutb) {
    int idx = blockIdx.x * 256 + threadIdx.x;
    int b = idx >> 10;
    int h = idx & (H - 1);
    float ig = b_ih[h]         + b_hh[h];
    float fg = b_ih[H + h]     + b_hh[H + h];
    float gg = b_ih[2 * H + h] + b_hh[2 * H + h];
    float og = b_ih[3 * H + h] + b_hh[3 * H + h];
#pragma unroll
    for (int p = 0; p < KSPLIT; p++) {
        const float* g = gpart + ((size_t)p * B + b) * G4;
        ig += g[h]; fg += g[H + h]; gg += g[2 * H + h]; og += g[3 * H + h];
    }
    float si = 1.f / (1.f + expf(-ig));
    float sf = 1.f / (1.f + expf(-fg));
    float so = 1.f / (1.f + expf(-og));
    float c = sf * cell[idx] + si * tanhf(gg);
    float hn = so * tanhf(c);
    out_h[idx] = hn;
    out_c[idx] = c;
    xoutb[(size_t)b * H2 + h] = f2bf(hn);
    xoutb[(size_t)b * H2 + H + h] = xinb[(size_t)b * KG + E + h];
}

// ---------------------------------------------------------------------------
// fc GEMM: M=128 N=32000 K=2048. BM=128, BN=32, BK=32, grid 1000 (~4 blk/CU).
// Same template as gates: glds16-everything (B fp32), swizzled, dbuf,
// one barrier per iter. B stream = 262 MB is the roofline term.
// ---------------------------------------------------------------------------
__global__ __launch_bounds__(256) void k_fc_mfma(const short* __restrict__ xoutb,
                                                 const float* __restrict__ fcW,
                                                 const float* __restrict__ fcb,
                                                 float* __restrict__ logits) {
    __shared__ __align__(16) short A_s[2 * 4096];   // 16 KB
    __shared__ __align__(16) float B_s[2 * 1024];   // 8 KB

    const int tid  = threadIdx.x;
    const int wave = tid >> 6, lane = tid & 63;
    const int c16 = lane & 15, q4 = lane >> 4;
    const int n0 = blockIdx.x * 32;

    const int scA   = ((lane & 3) ^ ((lane >> 3) & 3)) * 8;
    const int rowA0 = wave * 32 + (lane >> 2);
    const int rowA1 = rowA0 + 16;
    const int rowB  = wave * 8 + (lane >> 3);
    const int scB   = ((lane & 7) ^ ((lane >> 3) & 7)) * 4;
    const int sa = (c16 >> 1) & 3;
    const int sb = c16 & 7;

    const short* gA0 = xoutb + (size_t)rowA0 * H2 + scA;
    const short* gA1 = xoutb + (size_t)rowA1 * H2 + scA;
    const float* gBr = fcW + (size_t)(n0 + rowB) * H2 + scB;

    auto stage = [&](int k0, int abo, int bbo) {
        glds16(gA0 + k0, A_s + abo + wave * 1024);
        glds16(gA1 + k0, A_s + abo + wave * 1024 + 512);
        glds16(gBr + k0, B_s + bbo + wave * 256);
    };

    f32x4 acc[2][2] = {};
    stage(0, 0, 0);
    __syncthreads();

    for (int kk = 0; kk < H2 / 32; kk++) {
        const int abo = (kk & 1) << 12;
        const int bbo = (kk & 1) << 10;
        if (kk < H2 / 32 - 1) stage((kk + 1) * 32, abo ^ 4096, bbo ^ 1024);

        short8 a[2], bfr[2];
#pragma unroll
        for (int i = 0; i < 2; i++) {
            int r = wave * 32 + i * 16 + c16;
            a[i] = *(const short8*)(A_s + abo + r * 32 + (q4 ^ sa) * 8);
        }
#pragma unroll
        for (int j = 0; j < 2; j++) {
            int rb = j * 16 + c16;
            int cl = (2 * q4) ^ sb;
            float4 lo = *(const float4*)(B_s + bbo + rb * 32 + cl * 4);
            float4 hi = *(const float4*)(B_s + bbo + rb * 32 + (cl ^ 1) * 4);
            bfr[j] = cvt8(lo, hi);
        }
#pragma unroll
        for (int i = 0; i < 2; i++)
#pragma unroll
            for (int j = 0; j < 2; j++)
                acc[i][j] = __builtin_amdgcn_mfma_f32_16x16x32_bf16(a[i], bfr[j], acc[i][j], 0, 0, 0);

        if (kk < H2 / 32 - 1) __syncthreads();
    }

#pragma unroll
    for (int i = 0; i < 2; i++)
#pragma unroll
        for (int j = 0; j < 2; j++) {
            int n = n0 + j * 16 + c16;
            float bias = fcb[n];
#pragma unroll
            for (int r = 0; r < 4; r++) {
                int R = wave * 32 + i * 16 + q4 * 4 + r;
                logits[(size_t)R * V + n] = acc[i][j][r] + bias;
            }
        }
}

// ---------------------------------------------------------------------------
extern "C" void kernel_launch(void* const* d_in, const int* in_sizes, int n_in,
                              void* d_out, int out_size, void* d_ws, size_t ws_size,
                              hipStream_t stream) {
    const int*   x      = (const int*)d_in[0];
    const float* hidden = (const float*)d_in[1];
    const float* cell   = (const float*)d_in[2];
    const float* enc    = (const float*)d_in[3];
    const float* emb    = (const float*)d_in[4];
    const float* attn_W = (const float*)d_in[5];
    const float* attn_b = (const float*)d_in[6];
    const float* v      = (const float*)d_in[7];
    const float* W_ih   = (const float*)d_in[8];
    const float* W_hh   = (const float*)d_in[9];
    const float* b_ih   = (const float*)d_in[10];
    const float* b_hh   = (const float*)d_in[11];
    const float* fc_W   = (const float*)d_in[12];
    const float* fc_b   = (const float*)d_in[13];

    float* out = (float*)d_out;
    float* logits   = out;                                   // [B,V]
    float* out_h    = out + (size_t)B * V;                   // [1,B,H]
    float* out_c    = out_h + (size_t)B * H;                 // [1,B,H]
    float* out_attn = out_c + (size_t)B * H;                 // [B,S]

    // workspace layout (16B-aligned)
    char* ws = (char*)d_ws;
    short* encb  = (short*)ws;   ws += (size_t)BS * H * 2;   // 33.5 MB
    short* w2b   = (short*)ws;   ws += (size_t)H * H * 2;    // 2 MB
    short* xinb  = (short*)ws;   ws += (size_t)B * KG * 2;   // 0.66 MB
    short* xoutb = (short*)ws;   ws += (size_t)B * H2 * 2;   // 0.5 MB
    float* q     = (float*)ws;   ws += (size_t)B * H * 4;
    float* part  = (float*)ws;   ws += (size_t)BS * 8 * 4;
    float* gpart = (float*)ws;   ws += (size_t)KSPLIT * B * G4 * 4;  // 8 MB

    k_pre<<<dim3(512 + 16384 + 1024), dim3(256), 0, stream>>>(enc, encb, attn_W, w2b,
                                                              hidden, attn_b, q);
    k_energy_mfma<<<dim3(BS / 128, H / 128), dim3(256), 0, stream>>>(encb, w2b, q, v, part);
    k_softmax_ctx<<<dim3(B * 4), dim3(256), 0, stream>>>(part, encb, x, emb, hidden, out_attn, xinb);
    k_gates_mfma<<<dim3(G4 / 32, KSPLIT), dim3(256), 0, stream>>>(xinb, W_ih, W_hh, gpart);
    k_lstm<<<dim3(B * H / 256), dim3(256), 0, stream>>>(gpart, cell, b_ih, b_hh, xinb,
                                                        out_h, out_c, xoutb);
    k_fc_mfma<<<dim3(V / 32), dim3(256), 0, stream>>>(xoutb, fc_W, fc_b, logits);
}

// Round 4
// 580.948 us; speedup vs baseline: 1.2602x; 1.1033x over previous
//
#include <hip/hip_runtime.h>
#include <hip/hip_bf16.h>
#include <math.h>

// Problem constants
constexpr int B  = 128;
constexpr int S  = 128;
constexpr int H  = 1024;
constexpr int E  = 512;
constexpr int V  = 32000;
constexpr int H2 = 2 * H;     // 2048
constexpr int G4 = 4 * H;     // 4096
constexpr int KX = E + H;     // 1536
constexpr int KG = KX + H;    // 2560
constexpr int BS = B * S;     // 16384
constexpr int KSPLIT = 4;
constexpr int KSEG = KG / KSPLIT;  // 640
constexpr int QSPLIT = 4;
constexpr int QSEG = H / QSPLIT;   // 256

typedef float  f32x4  __attribute__((ext_vector_type(4)));
typedef short  short8 __attribute__((ext_vector_type(8)));

// counted-vmcnt pipeline primitives (T4): keep next-tile loads in flight
// across the barrier; raw s_barrier (no implicit vmcnt(0) drain).
#define VMCNT(N) asm volatile("s_waitcnt vmcnt(" #N ")" ::: "memory")
#define SBAR     asm volatile("s_barrier" ::: "memory")
#define SCHED0   __builtin_amdgcn_sched_barrier(0)

// fp32 -> bf16 round-to-nearest-even
__device__ __forceinline__ short f2bf(float f) {
    union { float f; unsigned u; } x; x.f = f;
    unsigned r = (x.u + 0x7FFFu + ((x.u >> 16) & 1u)) >> 16;
    return (short)r;
}
__device__ __forceinline__ float bf2f(unsigned short u) {
    union { unsigned u; float f; } x; x.u = ((unsigned)u) << 16;
    return x.f;
}
__device__ __forceinline__ float fast_tanh(float x) {
    float z = fminf(fmaxf(x, -15.f), 15.f);
    float e = __expf(2.f * z);
    return 1.f - __fdividef(2.f, e + 1.f);
}
__device__ __forceinline__ short8 cvt8(float4 a, float4 b) {
    short8 r;
    r[0] = f2bf(a.x); r[1] = f2bf(a.y); r[2] = f2bf(a.z); r[3] = f2bf(a.w);
    r[4] = f2bf(b.x); r[5] = f2bf(b.y); r[6] = f2bf(b.z); r[7] = f2bf(b.w);
    return r;
}
// async global->LDS, 16B/lane; LDS dest = wave-uniform base + lane*16
__device__ __forceinline__ void glds16(const void* g, void* l) {
    __builtin_amdgcn_global_load_lds(
        (const __attribute__((address_space(1))) unsigned int*)g,
        (__attribute__((address_space(3))) unsigned int*)l,
        16, 0, 0);
}

// ---------------------------------------------------------------------------
// Pure conversion: enc->bf16 (16384 blocks), attn_W[:,H:]->bf16 (1024).
// (q moved to its own MFMA kernel.)
// ---------------------------------------------------------------------------
__global__ __launch_bounds__(256) void k_pre(const float* __restrict__ enc,
                                             short* __restrict__ encb,
                                             const float* __restrict__ attn_W,
                                             short* __restrict__ w2b) {
    int bid = blockIdx.x;
    if (bid < 16384) {
        size_t p = (size_t)bid * 256 + threadIdx.x;
        float4 a = *(const float4*)(enc + p * 4);
        short4 o = { f2bf(a.x), f2bf(a.y), f2bf(a.z), f2bf(a.w) };
        *(short4*)(encb + p * 4) = o;
    } else {
        int p = (bid - 16384) * 256 + threadIdx.x;
        int row = p >> 8;
        int c = (p & 255) * 4;
        float4 a = *(const float4*)(attn_W + (size_t)row * H2 + H + c);
        short4 o = { f2bf(a.x), f2bf(a.y), f2bf(a.z), f2bf(a.w) };
        *(short4*)(w2b + (size_t)row * H + c) = o;
    }
}

// ---------------------------------------------------------------------------
// q MFMA GEMM: qpart[kh][b][n] = hlast[b,:] @ attn_W[n, kh*256:+256]
// M=128, N=1024(h), K=1024, BN=32, BK=32, K-split 4. Grid (32,4).
// A (hlast) and B (attn_W[:, :H]) both fp32, staged via glds16 with
// chunk swizzle, converted to bf16 at fragment read. Counted-vmcnt pipeline.
// ---------------------------------------------------------------------------
__global__ __launch_bounds__(256) void k_q_mfma(const float* __restrict__ hlast,
                                                const float* __restrict__ attn_W,
                                                float* __restrict__ qpart) {
    __shared__ __align__(16) float A_s[2 * 4096];   // 128x32 fp32 x2 = 32 KB
    __shared__ __align__(16) float B_s[2 * 1024];   // 32x32 fp32 x2 = 8 KB

    const int tid  = threadIdx.x;
    const int wave = tid >> 6, lane = tid & 63;
    const int c16 = lane & 15, q4 = lane >> 4;
    const int n0 = blockIdx.x * 32;
    const int kbeg = blockIdx.y * QSEG;

    // fp32 rows = 8 chunks of 16B; src chunk = dest chunk ^ (row&7)
    const int sc = ((lane & 7) ^ ((lane >> 3) & 7)) * 4;   // float offset
    const int rA = (lane >> 3);                            // + wave*32 + j*8
    const int rowB = wave * 8 + (lane >> 3);

    const float* gB = attn_W + (size_t)(n0 + rowB) * H2 + sc;

    auto stage = [&](int k0, int abo, int bbo) {
#pragma unroll
        for (int j = 0; j < 4; j++) {
            int row = wave * 32 + j * 8 + rA;
            glds16(hlast + (size_t)row * H + k0 + sc,
                   A_s + abo + wave * 1024 + j * 256);
        }
        glds16(gB + k0, B_s + bbo + wave * 256);
    };

    f32x4 acc[2][2] = {};
    stage(kbeg, 0, 0);

    for (int kk = 0; kk < QSEG / 32; kk++) {
        const int abo = (kk & 1) << 12;
        const int bbo = (kk & 1) << 10;
        if (kk < QSEG / 32 - 1) {
            stage(kbeg + (kk + 1) * 32, abo ^ 4096, bbo ^ 1024);
            VMCNT(5);
        } else {
            VMCNT(0);
        }
        SCHED0; SBAR;

        short8 a[2], bfr[2];
#pragma unroll
        for (int i = 0; i < 2; i++) {
            int ar = wave * 32 + i * 16 + c16;
            int cl = (2 * q4) ^ (ar & 7);
            float4 lo = *(const float4*)(A_s + abo + ar * 32 + cl * 4);
            float4 hi = *(const float4*)(A_s + abo + ar * 32 + (cl ^ 1) * 4);
            a[i] = cvt8(lo, hi);
        }
#pragma unroll
        for (int j = 0; j < 2; j++) {
            int rb = j * 16 + c16;
            int cl = (2 * q4) ^ (rb & 7);
            float4 lo = *(const float4*)(B_s + bbo + rb * 32 + cl * 4);
            float4 hi = *(const float4*)(B_s + bbo + rb * 32 + (cl ^ 1) * 4);
            bfr[j] = cvt8(lo, hi);
        }
#pragma unroll
        for (int i = 0; i < 2; i++)
#pragma unroll
            for (int j = 0; j < 2; j++)
                acc[i][j] = __builtin_amdgcn_mfma_f32_16x16x32_bf16(a[i], bfr[j], acc[i][j], 0, 0, 0);

        SCHED0; SBAR;
    }

    float* qp = qpart + (size_t)blockIdx.y * B * H;
#pragma unroll
    for (int i = 0; i < 2; i++)
#pragma unroll
        for (int j = 0; j < 2; j++)
#pragma unroll
            for (int r = 0; r < 4; r++) {
                int R = wave * 32 + i * 16 + q4 * 4 + r;
                int n = n0 + j * 16 + c16;
                qp[(size_t)R * H + n] = acc[i][j][r];
            }
}

// ---------------------------------------------------------------------------
// Energy MFMA GEMM + fused tanh/v/row-reduce. Counted-vmcnt pipeline (C=4).
// red[] aliases the tile buffers (used only after the K-loop, fenced).
// ---------------------------------------------------------------------------
__global__ __launch_bounds__(256) void k_energy_mfma(const short* __restrict__ encb,
                                                     const short* __restrict__ w2b,
                                                     const float* __restrict__ qpart,
                                                     const float* __restrict__ attn_b,
                                                     const float* __restrict__ v,
                                                     float* __restrict__ part) {
    __shared__ __align__(16) char smem[32768];
    short* Af = (short*)smem;                 // [2][4096] shorts (16 KB)
    short* Bf = (short*)(smem + 16384);       // [2][4096] shorts (16 KB)
    float (*red)[33] = (float(*)[33])smem;    // 16.9 KB, aliases tiles

    const int tid  = threadIdx.x;
    const int wave = tid >> 6, lane = tid & 63;
    const int wr = wave >> 1, wc = wave & 1;
    const int c16 = lane & 15, q4 = lane >> 4;
    const int m0 = blockIdx.x * 128;
    const int n0 = blockIdx.y * 128;

    f32x4 acc[4][4] = {};

    const int scA   = ((lane & 3) ^ ((lane >> 3) & 3)) * 8;   // src short-ofs
    const int rowA0 = wave * 32 + (lane >> 2);
    const int rowA1 = rowA0 + 16;
    const int sa    = (c16 >> 1) & 3;                          // read swizzle

    const short* gA = encb + (size_t)m0 * H;
    const short* gB = w2b + (size_t)n0 * H;

    auto stage = [&](int k0, int dst) {
        glds16(gA + (size_t)rowA0 * H + k0 + scA, Af + dst + wave * 1024);
        glds16(gA + (size_t)rowA1 * H + k0 + scA, Af + dst + wave * 1024 + 512);
        glds16(gB + (size_t)rowA0 * H + k0 + scA, Bf + dst + wave * 1024);
        glds16(gB + (size_t)rowA1 * H + k0 + scA, Bf + dst + wave * 1024 + 512);
    };

    stage(0, 0);

    for (int kk = 0; kk < 32; kk++) {
        const int bo = (kk & 1) << 12;
        if (kk < 31) {
            stage((kk + 1) * 32, bo ^ 4096);
            VMCNT(4);
        } else {
            VMCNT(0);
        }
        SCHED0; SBAR;

        short8 a[4], b[4];
#pragma unroll
        for (int i = 0; i < 4; i++) {
            int r = wr * 64 + i * 16 + c16;
            a[i] = *(const short8*)(Af + bo + r * 32 + (q4 ^ sa) * 8);
        }
#pragma unroll
        for (int j = 0; j < 4; j++) {
            int r = wc * 64 + j * 16 + c16;
            b[j] = *(const short8*)(Bf + bo + r * 32 + (q4 ^ sa) * 8);
        }
#pragma unroll
        for (int i = 0; i < 4; i++)
#pragma unroll
            for (int j = 0; j < 4; j++)
                acc[i][j] = __builtin_amdgcn_mfma_f32_16x16x32_bf16(a[i], b[j], acc[i][j], 0, 0, 0);

        SCHED0; SBAR;
    }

    // per-thread q and v values for the 4 n-columns (hoisted; L2-hot)
    const int bb = blockIdx.x;          // b == blockIdx.x (BM==S)
    float qv[4], vv[4];
#pragma unroll
    for (int j = 0; j < 4; j++) {
        int n = n0 + wc * 64 + j * 16 + c16;
        float s = attn_b[n];
#pragma unroll
        for (int kh = 0; kh < QSPLIT; kh++)
            s += qpart[((size_t)kh * B + bb) * H + n];
        qv[j] = s;
        vv[j] = v[n];
    }

#pragma unroll
    for (int i = 0; i < 4; i++) {
#pragma unroll
        for (int r = 0; r < 4; r++) {
            float s = 0.f;
#pragma unroll
            for (int j = 0; j < 4; j++)
                s += vv[j] * fast_tanh(qv[j] + acc[i][j][r]);
            red[wr * 64 + i * 16 + q4 * 4 + r][wc * 16 + c16] = s;
        }
    }
    __syncthreads();
    if (tid < 128) {
        float s = 0.f;
#pragma unroll
        for (int c = 0; c < 32; c++) s += red[tid][c];
        part[(size_t)(m0 + tid) * 8 + blockIdx.y] = s;
    }
}

// ---------------------------------------------------------------------------
// Softmax over S + context, fused with xin packing (4 chunks per b).
// ---------------------------------------------------------------------------
__global__ __launch_bounds__(256) void k_softmax_ctx(const float* __restrict__ part,
                                                     const short* __restrict__ encb,
                                                     const int* __restrict__ x,
                                                     const float* __restrict__ emb,
                                                     const float* __restrict__ hlast,
                                                     float* __restrict__ attn_out,
                                                     short* __restrict__ xinb) {
    const int bid = blockIdx.x;
    const int b = bid >> 2, ch = bid & 3;
    const int tid = threadIdx.x;
    __shared__ float w[S];
    __shared__ float red[128];

    float val = 0.f;
    if (tid < S) {
        const float* p = part + (size_t)(b * S + tid) * 8;
#pragma unroll
        for (int t = 0; t < 8; t++) val += p[t];
        w[tid] = val;
        red[tid] = val;
    }
    __syncthreads();
#pragma unroll
    for (int s = 64; s > 0; s >>= 1) {
        if (tid < s) red[tid] = fmaxf(red[tid], red[tid + s]);
        __syncthreads();
    }
    float m = red[0];
    __syncthreads();
    if (tid < S) { val = __expf(w[tid] - m); red[tid] = val; }
    __syncthreads();
#pragma unroll
    for (int s = 64; s > 0; s >>= 1) {
        if (tid < s) red[tid] += red[tid + s];
        __syncthreads();
    }
    float inv = 1.f / red[0];
    if (tid < S) {
        val *= inv;
        w[tid] = val;
        if (ch == 0) attn_out[b * S + tid] = val;
    }
    if (ch == 1) {
        int xv = x[b];
        float2 e2 = *(const float2*)(emb + (size_t)xv * E + tid * 2);
        short2 eo = { f2bf(e2.x), f2bf(e2.y) };
        *(short2*)(xinb + (size_t)b * KG + tid * 2) = eo;
    } else if (ch == 2) {
        float4 h4 = *(const float4*)(hlast + (size_t)b * H + tid * 4);
        short4 ho = { f2bf(h4.x), f2bf(h4.y), f2bf(h4.z), f2bf(h4.w) };
        *(short4*)(xinb + (size_t)b * KG + KX + tid * 4) = ho;
    }
    __syncthreads();

    const int h = ch * 256 + tid;
    const unsigned short* e = (const unsigned short*)encb + (size_t)b * S * H + h;
    float a0 = 0.f;
#pragma unroll 8
    for (int s = 0; s < S; s++) a0 += w[s] * bf2f(e[(size_t)s * H]);
    xinb[(size_t)b * KG + E + h] = f2bf(a0);
}

// ---------------------------------------------------------------------------
// Gates GEMM: M=128, BN=32, BK=32, K-split 4 (grid 128x4). Counted-vmcnt (C=3).
// ---------------------------------------------------------------------------
__global__ __launch_bounds__(256) void k_gates_mfma(const short* __restrict__ xinb,
                                                    const float* __restrict__ W_ih,
                                                    const float* __restrict__ W_hh,
                                                    float* __restrict__ gpart) {
    __shared__ __align__(16) short A_s[2 * 4096];   // 16 KB
    __shared__ __align__(16) float B_s[2 * 1024];   // 8 KB (fp32 32x32)

    const int tid  = threadIdx.x;
    const int wave = tid >> 6, lane = tid & 63;
    const int c16 = lane & 15, q4 = lane >> 4;
    const int n0 = blockIdx.x * 32;
    const int kbeg = blockIdx.y * KSEG;

    const int scA   = ((lane & 3) ^ ((lane >> 3) & 3)) * 8;
    const int rowA0 = wave * 32 + (lane >> 2);
    const int rowA1 = rowA0 + 16;
    const int rowB  = wave * 8 + (lane >> 3);
    const int scB   = ((lane & 7) ^ ((lane >> 3) & 7)) * 4;
    const int sa = (c16 >> 1) & 3;
    const int sb = c16 & 7;

    const short* gA0 = xinb + (size_t)rowA0 * KG + scA;
    const short* gA1 = xinb + (size_t)rowA1 * KG + scA;
    const int nr = n0 + rowB;

    auto bsrc = [&](int k0) -> const float* {
        return (k0 < KX) ? (W_ih + (size_t)nr * KX + k0 + scB)
                         : (W_hh + (size_t)nr * H + (k0 - KX) + scB);
    };
    auto stage = [&](int k0, int abo, int bbo) {
        glds16(gA0 + k0, A_s + abo + wave * 1024);
        glds16(gA1 + k0, A_s + abo + wave * 1024 + 512);
        glds16(bsrc(k0), B_s + bbo + wave * 256);
    };

    f32x4 acc[2][2] = {};
    stage(kbeg, 0, 0);

    for (int kk = 0; kk < KSEG / 32; kk++) {
        const int abo = (kk & 1) << 12;
        const int bbo = (kk & 1) << 10;
        if (kk < KSEG / 32 - 1) {
            stage(kbeg + (kk + 1) * 32, abo ^ 4096, bbo ^ 1024);
            VMCNT(3);
        } else {
            VMCNT(0);
        }
        SCHED0; SBAR;

        short8 a[2], bfr[2];
#pragma unroll
        for (int i = 0; i < 2; i++) {
            int r = wave * 32 + i * 16 + c16;
            a[i] = *(const short8*)(A_s + abo + r * 32 + (q4 ^ sa) * 8);
        }
#pragma unroll
        for (int j = 0; j < 2; j++) {
            int rb = j * 16 + c16;
            int cl = (2 * q4) ^ sb;
            float4 lo = *(const float4*)(B_s + bbo + rb * 32 + cl * 4);
            float4 hi = *(const float4*)(B_s + bbo + rb * 32 + (cl ^ 1) * 4);
            bfr[j] = cvt8(lo, hi);
        }
#pragma unroll
        for (int i = 0; i < 2; i++)
#pragma unroll
            for (int j = 0; j < 2; j++)
                acc[i][j] = __builtin_amdgcn_mfma_f32_16x16x32_bf16(a[i], bfr[j], acc[i][j], 0, 0, 0);

        SCHED0; SBAR;
    }

    float* gp = gpart + (size_t)blockIdx.y * B * G4;
#pragma unroll
    for (int i = 0; i < 2; i++)
#pragma unroll
        for (int j = 0; j < 2; j++)
#pragma unroll
            for (int r = 0; r < 4; r++) {
                int R = wave * 32 + i * 16 + q4 * 4 + r;
                int n = n0 + j * 16 + c16;
                gp[(size_t)R * G4 + n] = acc[i][j][r];
            }
}

// ---------------------------------------------------------------------------
// LSTM pointwise; sums KSPLIT gate partials + biases.
// ---------------------------------------------------------------------------
__global__ __launch_bounds__(256) void k_lstm(const float* __restrict__ gpart,
                                              const float* __restrict__ cell,
                                              const float* __restrict__ b_ih,
                                              const float* __restrict__ b_hh,
                                              const short* __restrict__ xinb,
                                              float* __restrict__ out_h,
                                              float* __restrict__ out_c,
                                              short* __restrict__ xoutb) {
    int idx = blockIdx.x * 256 + threadIdx.x;
    int b = idx >> 10;
    int h = idx & (H - 1);
    float ig = b_ih[h]         + b_hh[h];
    float fg = b_ih[H + h]     + b_hh[H + h];
    float gg = b_ih[2 * H + h] + b_hh[2 * H + h];
    float og = b_ih[3 * H + h] + b_hh[3 * H + h];
#pragma unroll
    for (int p = 0; p < KSPLIT; p++) {
        const float* g = gpart + ((size_t)p * B + b) * G4;
        ig += g[h]; fg += g[H + h]; gg += g[2 * H + h]; og += g[3 * H + h];
    }
    float si = 1.f / (1.f + expf(-ig));
    float sf = 1.f / (1.f + expf(-fg));
    float so = 1.f / (1.f + expf(-og));
    float c = sf * cell[idx] + si * tanhf(gg);
    float hn = so * tanhf(c);
    out_h[idx] = hn;
    out_c[idx] = c;
    xoutb[(size_t)b * H2 + h] = f2bf(hn);
    xoutb[(size_t)b * H2 + H + h] = xinb[(size_t)b * KG + E + h];
}

// ---------------------------------------------------------------------------
// fc GEMM: M=128 N=32000 K=2048. BM=128, BN=32, BK=32, grid 1000.
// Counted-vmcnt pipeline (C=3). B stream = 262 MB fp32 is the roofline term.
// ---------------------------------------------------------------------------
__global__ __launch_bounds__(256) void k_fc_mfma(const short* __restrict__ xoutb,
                                                 const float* __restrict__ fcW,
                                                 const float* __restrict__ fcb,
                                                 float* __restrict__ logits) {
    __shared__ __align__(16) short A_s[2 * 4096];   // 16 KB
    __shared__ __align__(16) float B_s[2 * 1024];   // 8 KB

    const int tid  = threadIdx.x;
    const int wave = tid >> 6, lane = tid & 63;
    const int c16 = lane & 15, q4 = lane >> 4;
    const int n0 = blockIdx.x * 32;

    const int scA   = ((lane & 3) ^ ((lane >> 3) & 3)) * 8;
    const int rowA0 = wave * 32 + (lane >> 2);
    const int rowA1 = rowA0 + 16;
    const int rowB  = wave * 8 + (lane >> 3);
    const int scB   = ((lane & 7) ^ ((lane >> 3) & 7)) * 4;
    const int sa = (c16 >> 1) & 3;
    const int sb = c16 & 7;

    const short* gA0 = xoutb + (size_t)rowA0 * H2 + scA;
    const short* gA1 = xoutb + (size_t)rowA1 * H2 + scA;
    const float* gBr = fcW + (size_t)(n0 + rowB) * H2 + scB;

    auto stage = [&](int k0, int abo, int bbo) {
        glds16(gA0 + k0, A_s + abo + wave * 1024);
        glds16(gA1 + k0, A_s + abo + wave * 1024 + 512);
        glds16(gBr + k0, B_s + bbo + wave * 256);
    };

    f32x4 acc[2][2] = {};
    stage(0, 0, 0);

    for (int kk = 0; kk < H2 / 32; kk++) {
        const int abo = (kk & 1) << 12;
        const int bbo = (kk & 1) << 10;
        if (kk < H2 / 32 - 1) {
            stage((kk + 1) * 32, abo ^ 4096, bbo ^ 1024);
            VMCNT(3);
        } else {
            VMCNT(0);
        }
        SCHED0; SBAR;

        short8 a[2], bfr[2];
#pragma unroll
        for (int i = 0; i < 2; i++) {
            int r = wave * 32 + i * 16 + c16;
            a[i] = *(const short8*)(A_s + abo + r * 32 + (q4 ^ sa) * 8);
        }
#pragma unroll
        for (int j = 0; j < 2; j++) {
            int rb = j * 16 + c16;
            int cl = (2 * q4) ^ sb;
            float4 lo = *(const float4*)(B_s + bbo + rb * 32 + cl * 4);
            float4 hi = *(const float4*)(B_s + bbo + rb * 32 + (cl ^ 1) * 4);
            bfr[j] = cvt8(lo, hi);
        }
#pragma unroll
        for (int i = 0; i < 2; i++)
#pragma unroll
            for (int j = 0; j < 2; j++)
                acc[i][j] = __builtin_amdgcn_mfma_f32_16x16x32_bf16(a[i], bfr[j], acc[i][j], 0, 0, 0);

        SCHED0; SBAR;
    }

#pragma unroll
    for (int i = 0; i < 2; i++)
#pragma unroll
        for (int j = 0; j < 2; j++) {
            int n = n0 + j * 16 + c16;
            float bias = fcb[n];
#pragma unroll
            for (int r = 0; r < 4; r++) {
                int R = wave * 32 + i * 16 + q4 * 4 + r;
                logits[(size_t)R * V + n] = acc[i][j][r] + bias;
            }
        }
}

// ---------------------------------------------------------------------------
extern "C" void kernel_launch(void* const* d_in, const int* in_sizes, int n_in,
                              void* d_out, int out_size, void* d_ws, size_t ws_size,
                              hipStream_t stream) {
    const int*   x      = (const int*)d_in[0];
    const float* hidden = (const float*)d_in[1];
    const float* cell   = (const float*)d_in[2];
    const float* enc    = (const float*)d_in[3];
    const float* emb    = (const float*)d_in[4];
    const float* attn_W = (const float*)d_in[5];
    const float* attn_b = (const float*)d_in[6];
    const float* v      = (const float*)d_in[7];
    const float* W_ih   = (const float*)d_in[8];
    const float* W_hh   = (const float*)d_in[9];
    const float* b_ih   = (const float*)d_in[10];
    const float* b_hh   = (const float*)d_in[11];
    const float* fc_W   = (const float*)d_in[12];
    const float* fc_b   = (const float*)d_in[13];

    float* out = (float*)d_out;
    float* logits   = out;                                   // [B,V]
    float* out_h    = out + (size_t)B * V;                   // [1,B,H]
    float* out_c    = out_h + (size_t)B * H;                 // [1,B,H]
    float* out_attn = out_c + (size_t)B * H;                 // [B,S]

    // workspace layout (16B-aligned)
    char* ws = (char*)d_ws;
    short* encb  = (short*)ws;   ws += (size_t)BS * H * 2;   // 33.5 MB
    short* w2b   = (short*)ws;   ws += (size_t)H * H * 2;    // 2 MB
    short* xinb  = (short*)ws;   ws += (size_t)B * KG * 2;   // 0.66 MB
    short* xoutb = (short*)ws;   ws += (size_t)B * H2 * 2;   // 0.5 MB
    float* qpart = (float*)ws;   ws += (size_t)QSPLIT * B * H * 4;  // 2 MB
    float* part  = (float*)ws;   ws += (size_t)BS * 8 * 4;
    float* gpart = (float*)ws;   ws += (size_t)KSPLIT * B * G4 * 4; // 8 MB

    k_q_mfma<<<dim3(H / 32, QSPLIT), dim3(256), 0, stream>>>(hidden, attn_W, qpart);
    k_pre<<<dim3(16384 + 1024), dim3(256), 0, stream>>>(enc, encb, attn_W, w2b);
    k_energy_mfma<<<dim3(BS / 128, H / 128), dim3(256), 0, stream>>>(encb, w2b, qpart,
                                                                     attn_b, v, part);
    k_softmax_ctx<<<dim3(B * 4), dim3(256), 0, stream>>>(part, encb, x, emb, hidden, out_attn, xinb);
    k_gates_mfma<<<dim3(G4 / 32, KSPLIT), dim3(256), 0, stream>>>(xinb, W_ih, W_hh, gpart);
    k_lstm<<<dim3(B * H / 256), dim3(256), 0, stream>>>(gpart, cell, b_ih, b_hh, xinb,
                                                        out_h, out_c, xoutb);
    k_fc_mfma<<<dim3(V / 32), dim3(256), 0, stream>>>(xoutb, fc_W, fc_b, logits);
}